// Round 2
// baseline (303.680 us; speedup 1.0000x reference)
//
#include <hip/hip_runtime.h>
#include <math.h>

// YOLO loss: pred/target (BATCH,7,7,30) f32, choice (BATCH,7,7) i32
// -> 4 scalars (loc, cls, obj, noobj).
// Round-2: round-1 was L1/TA transaction-bound (stride-120B float2 loads touch
// 64 lines/instr; L3-warm replay showed identical 93us -> not HBM-bound).
// Fix: coalesced float4 staging into LDS (16 lines/instr, each line once).

constexpr int NCH = 30;   // 5*B + C
constexpr int CC  = 20;   // classes
constexpr int PAD = 16;   // floats per accumulator slot (64 B apart)
constexpr int T   = 128;  // threads per block (2 waves)
constexpr int CPB = 128;  // cells per block
constexpr int NV  = CPB * NCH / 4;  // 960 float4 per input chunk

__global__ __launch_bounds__(T) void yolo_main(
    const float* __restrict__ pred, const float* __restrict__ target,
    const int* __restrict__ choice, float* __restrict__ acc, int ncells)
{
    __shared__ float sbuf[2 * CPB * NCH];   // 30720 B: [pred chunk][target chunk]
    const int tid = threadIdx.x;
    const long long cell0 = (long long)blockIdx.x * CPB;
    const int remain = ncells - (int)cell0;

    if (remain >= CPB) {
        // fully coalesced: lane i loads base + i*16B -> 16 cache lines/instr,
        // every line touched exactly once
        const float4* Pg = (const float4*)(pred + cell0 * NCH);
        const float4* Tg = (const float4*)(target + cell0 * NCH);
        #pragma unroll
        for (int j = 0; j < 2 * NV / T; ++j) {   // 15 iters; k<NV wave-uniform
            int k = j * T + tid;
            float4 v;
            if (k < NV) v = Pg[k]; else v = Tg[k - NV];
            *(float4*)&sbuf[k * 4] = v;
        }
    } else {
        int nf = remain * NCH;
        for (int idx = tid; idx < nf; idx += T) {
            sbuf[idx]             = pred[cell0 * NCH + idx];
            sbuf[CPB * NCH + idx] = target[cell0 * NCH + idx];
        }
    }
    __syncthreads();

    float s_loc = 0.f, s_ce = 0.f, s_obj = 0.f, s_no = 0.f;
    float n_obj = 0.f, n_no = 0.f;

    if (cell0 + tid < ncells) {
        const float* sp  = &sbuf[tid * NCH];             // 120*tid B, 8-aligned
        const float* stt = &sbuf[CPB * NCH + tid * NCH];
        float p[NCH], t[NCH];
        #pragma unroll
        for (int i = 0; i < NCH / 2; ++i) {
            float2 v = *(const float2*)&sp[2 * i];  p[2*i] = v.x; p[2*i+1] = v.y;
        }
        #pragma unroll
        for (int i = 0; i < NCH / 2; ++i) {
            float2 w = *(const float2*)&stt[2 * i]; t[2*i] = w.x; t[2*i+1] = w.y;
        }
        bool c = choice[cell0 + tid] != 0;   // coalesced 4B/lane

        float tconf = t[4];
        bool  obj = tconf > 0.0f;
        float m = obj ? 1.0f : 0.0f;

        float pxy0 = c ? p[0] : p[5];
        float pxy1 = c ? p[1] : p[6];
        float pwh0 = c ? p[2] : p[7];
        float pwh1 = c ? p[3] : p[8];
        float pobj = c ? p[4] : p[9];
        float txy0 = c ? t[0] : t[5];
        float txy1 = c ? t[1] : t[6];
        float twh0 = c ? t[2] : t[7];
        float twh1 = c ? t[3] : t[8];
        if (!obj) { twh0 = 1.0f; twh1 = 1.0f; }
        float tobj = c ? tconf : t[9];

        float dx = pxy0 - txy0, dy = pxy1 - txy1;
        float dw = pwh0 - sqrtf(twh0), dh = pwh1 - sqrtf(twh1);
        s_loc = m * (0.5f * (dx * dx + dy * dy) + 0.5f * (dw * dw + dh * dh));

        float dob = pobj - tobj;
        s_obj = m * dob * dob;

        float nm = (tconf == 0.0f) ? 1.0f : 0.0f;
        float d4 = p[4] - tconf, d9 = p[9] - t[9];
        s_no = nm * (d4 * d4 + d9 * d9);

        n_obj = m;
        n_no  = nm;

        int   tcls  = 0;
        float tbest = t[10];
        #pragma unroll
        for (int i = 1; i < CC; ++i) {
            float v = t[10 + i];
            if (v > tbest) { tbest = v; tcls = i; }
        }
        float mx = p[10];
        #pragma unroll
        for (int i = 1; i < CC; ++i) mx = fmaxf(mx, p[10 + i]);
        float e[CC];
        float Z = 0.f;
        #pragma unroll
        for (int i = 0; i < CC; ++i) { e[i] = __expf(p[10 + i] - mx); Z += e[i]; }
        float rZ = 1.0f / Z;
        float Z2 = 0.f, sm_t = 0.f;
        #pragma unroll
        for (int i = 0; i < CC; ++i) {
            float sm = e[i] * rZ;          // in (0,1] -> exp safe
            Z2 += __expf(sm);
            if (i == tcls) sm_t = sm;
        }
        s_ce = m * (__logf(Z2) - sm_t);
    }

    // wave(64) shuffle reduction of the 6 partials
    #pragma unroll
    for (int off = 32; off > 0; off >>= 1) {
        s_loc += __shfl_down(s_loc, off);
        s_ce  += __shfl_down(s_ce,  off);
        s_obj += __shfl_down(s_obj, off);
        s_no  += __shfl_down(s_no,  off);
        n_obj += __shfl_down(n_obj, off);
        n_no  += __shfl_down(n_no,  off);
    }

    __shared__ float red[2][6];
    int wave = tid >> 6;
    int lane = tid & 63;
    if (lane == 0) {
        red[wave][0] = s_loc; red[wave][1] = s_ce;  red[wave][2] = s_obj;
        red[wave][3] = s_no;  red[wave][4] = n_obj; red[wave][5] = n_no;
    }
    __syncthreads();
    if (tid < 6) {
        float v = red[0][tid] + red[1][tid];
        atomicAdd(&acc[tid * PAD], v);
    }
}

__global__ void yolo_final(const float* __restrict__ acc, float* __restrict__ out) {
    float S_loc = acc[0 * PAD], S_ce = acc[1 * PAD], S_obj = acc[2 * PAD];
    float S_no  = acc[3 * PAD], N_ob = acc[4 * PAD], N_no = acc[5 * PAD];
    out[0] = 5.0f * S_loc;
    out[1] = S_ce / fmaxf(N_ob, 1.0f);
    out[2] = S_obj;
    out[3] = 0.5f * S_no / fmaxf(N_no, 1.0f);
}

extern "C" void kernel_launch(void* const* d_in, const int* in_sizes, int n_in,
                              void* d_out, int out_size, void* d_ws, size_t ws_size,
                              hipStream_t stream) {
    const float* pred   = (const float*)d_in[0];
    const float* target = (const float*)d_in[1];
    const int*   choice = (const int*)d_in[2];
    float* out = (float*)d_out;
    float* acc = (float*)d_ws;

    int ncells = in_sizes[2];                 // BATCH * S * S = 802816
    hipMemsetAsync(d_ws, 0, 6 * PAD * sizeof(float), stream);
    int blocks = (ncells + CPB - 1) / CPB;    // 6272
    yolo_main<<<blocks, T, 0, stream>>>(pred, target, choice, acc, ncells);
    yolo_final<<<1, 1, 0, stream>>>(acc, out);
}

// Round 3
// 215.979 us; speedup vs baseline: 1.4061x; 1.4061x over previous
//
#include <hip/hip_runtime.h>
#include <math.h>

// YOLO loss: pred/target (BATCH,7,7,30) f32, choice (BATCH,7,7) i32
// -> 4 scalars (loc, cls, obj, noobj).
// Round-3 theory: rounds 1+2 were bound by same-address atomicAdd
// serialization at L2 (~28 ns per atomic per counter line; dur scaled with
// block count, and L3-warm replay didn't help). Fix: NO atomics — each block
// writes 6 partials to its own workspace row; a second kernel reduces.
// Compute/load structure kept identical to round 1 (single-variable expt).

constexpr int NCH = 30;   // 5*B + C
constexpr int CC  = 20;   // classes
constexpr int ROW = 8;    // floats per block's partial row (32 B)

__global__ __launch_bounds__(256) void yolo_main(
    const float* __restrict__ pred, const float* __restrict__ target,
    const int* __restrict__ choice, float* __restrict__ ws, int ncells)
{
    int cell = blockIdx.x * 256 + threadIdx.x;

    float s_loc = 0.f, s_ce = 0.f, s_obj = 0.f, s_no = 0.f;
    float n_obj = 0.f, n_no = 0.f;

    if (cell < ncells) {
        const float2* P2 = (const float2*)(pred + (size_t)cell * NCH);
        const float2* T2 = (const float2*)(target + (size_t)cell * NCH);
        float p[NCH], t[NCH];
        #pragma unroll
        for (int i = 0; i < NCH / 2; ++i) {
            float2 v = P2[i]; p[2 * i] = v.x; p[2 * i + 1] = v.y;
        }
        #pragma unroll
        for (int i = 0; i < NCH / 2; ++i) {
            float2 w = T2[i]; t[2 * i] = w.x; t[2 * i + 1] = w.y;
        }
        bool c = choice[cell] != 0;

        float tconf = t[4];
        bool  obj = tconf > 0.0f;
        float m = obj ? 1.0f : 0.0f;

        float pxy0 = c ? p[0] : p[5];
        float pxy1 = c ? p[1] : p[6];
        float pwh0 = c ? p[2] : p[7];
        float pwh1 = c ? p[3] : p[8];
        float pobj = c ? p[4] : p[9];
        float txy0 = c ? t[0] : t[5];
        float txy1 = c ? t[1] : t[6];
        float twh0 = c ? t[2] : t[7];
        float twh1 = c ? t[3] : t[8];
        if (!obj) { twh0 = 1.0f; twh1 = 1.0f; }
        float tobj = c ? tconf : t[9];

        float dx = pxy0 - txy0, dy = pxy1 - txy1;
        float dw = pwh0 - sqrtf(twh0), dh = pwh1 - sqrtf(twh1);
        s_loc = m * (0.5f * (dx * dx + dy * dy) + 0.5f * (dw * dw + dh * dh));

        float dob = pobj - tobj;
        s_obj = m * dob * dob;

        float nm = (tconf == 0.0f) ? 1.0f : 0.0f;
        float d4 = p[4] - tconf, d9 = p[9] - t[9];
        s_no = nm * (d4 * d4 + d9 * d9);

        n_obj = m;
        n_no  = nm;

        int   tcls  = 0;
        float tbest = t[10];
        #pragma unroll
        for (int i = 1; i < CC; ++i) {
            float v = t[10 + i];
            if (v > tbest) { tbest = v; tcls = i; }
        }
        float mx = p[10];
        #pragma unroll
        for (int i = 1; i < CC; ++i) mx = fmaxf(mx, p[10 + i]);
        float e[CC];
        float Z = 0.f;
        #pragma unroll
        for (int i = 0; i < CC; ++i) { e[i] = __expf(p[10 + i] - mx); Z += e[i]; }
        float rZ = 1.0f / Z;
        float Z2 = 0.f, sm_t = 0.f;
        #pragma unroll
        for (int i = 0; i < CC; ++i) {
            float sm = e[i] * rZ;          // in (0,1] -> exp safe
            Z2 += __expf(sm);
            if (i == tcls) sm_t = sm;
        }
        s_ce = m * (__logf(Z2) - sm_t);
    }

    #pragma unroll
    for (int off = 32; off > 0; off >>= 1) {
        s_loc += __shfl_down(s_loc, off);
        s_ce  += __shfl_down(s_ce,  off);
        s_obj += __shfl_down(s_obj, off);
        s_no  += __shfl_down(s_no,  off);
        n_obj += __shfl_down(n_obj, off);
        n_no  += __shfl_down(n_no,  off);
    }

    __shared__ float red[4][6];
    int wave = threadIdx.x >> 6;
    int lane = threadIdx.x & 63;
    if (lane == 0) {
        red[wave][0] = s_loc; red[wave][1] = s_ce;  red[wave][2] = s_obj;
        red[wave][3] = s_no;  red[wave][4] = n_obj; red[wave][5] = n_no;
    }
    __syncthreads();
    // NO atomics: private row per block, plain coalesced store
    if (threadIdx.x < 6) {
        float v = red[0][threadIdx.x] + red[1][threadIdx.x] +
                  red[2][threadIdx.x] + red[3][threadIdx.x];
        ws[(size_t)blockIdx.x * ROW + threadIdx.x] = v;
    }
}

__global__ __launch_bounds__(256) void yolo_reduce(
    const float* __restrict__ ws, float* __restrict__ out, int nb)
{
    float s[6] = {0.f, 0.f, 0.f, 0.f, 0.f, 0.f};
    for (int b = threadIdx.x; b < nb; b += 256) {
        #pragma unroll
        for (int j = 0; j < 6; ++j) s[j] += ws[(size_t)b * ROW + j];
    }
    #pragma unroll
    for (int off = 32; off > 0; off >>= 1) {
        #pragma unroll
        for (int j = 0; j < 6; ++j) s[j] += __shfl_down(s[j], off);
    }
    __shared__ float red[4][6];
    int wave = threadIdx.x >> 6;
    int lane = threadIdx.x & 63;
    if (lane == 0) {
        #pragma unroll
        for (int j = 0; j < 6; ++j) red[wave][j] = s[j];
    }
    __syncthreads();
    if (threadIdx.x == 0) {
        float t[6];
        #pragma unroll
        for (int j = 0; j < 6; ++j)
            t[j] = red[0][j] + red[1][j] + red[2][j] + red[3][j];
        out[0] = 5.0f * t[0];                 // loc_loss  (L_COORD = 5)
        out[1] = t[1] / fmaxf(t[4], 1.0f);    // cls_loss
        out[2] = t[2];                        // obj_loss
        out[3] = 0.5f * t[3] / fmaxf(t[5], 1.0f); // noobj_loss (L_NOOBJ = 0.5)
    }
}

extern "C" void kernel_launch(void* const* d_in, const int* in_sizes, int n_in,
                              void* d_out, int out_size, void* d_ws, size_t ws_size,
                              hipStream_t stream) {
    const float* pred   = (const float*)d_in[0];
    const float* target = (const float*)d_in[1];
    const int*   choice = (const int*)d_in[2];
    float* out = (float*)d_out;
    float* ws  = (float*)d_ws;

    int ncells = in_sizes[2];                 // BATCH * S * S = 802816
    int blocks = (ncells + 255) / 256;        // 3136 exactly
    // ws usage: blocks * ROW * 4 B = 100 KB; every row is written before read
    yolo_main<<<blocks, 256, 0, stream>>>(pred, target, choice, ws, ncells);
    yolo_reduce<<<1, 256, 0, stream>>>(ws, out, blocks);
}

// Round 4
// 214.329 us; speedup vs baseline: 1.4169x; 1.0077x over previous
//
#include <hip/hip_runtime.h>
#include <math.h>

// YOLO loss: pred/target (BATCH,7,7,30) f32, choice (BATCH,7,7) i32
// -> 4 scalars (loc, cls, obj, noobj).
// Round-4: combine the two proven wins:
//  - round-2: coalesced float4 -> LDS staging (16 lines/instr, each line
//    requested once) removes the L1/TA transaction bottleneck (stride-120B
//    direct loads cost ~25M line-requests ~= 75us; staged ~3M ~= 5us).
//  - round-3: NO same-address atomics (each block writes a private ws row;
//    second kernel reduces). Atomics cost ~26ns/block serialized.
// Round-2 measured LDS bank conflicts are negligible (652k cyc / 256 CU ~ 1us).

constexpr int NCH = 30;   // 5*B + C
constexpr int CC  = 20;   // classes
constexpr int ROW = 8;    // floats per block's partial row (32 B)
constexpr int T   = 128;  // threads per block (2 waves)
constexpr int CPB = 128;  // cells per block
constexpr int NV  = CPB * NCH / 4;  // 960 float4 per input chunk

__global__ __launch_bounds__(T) void yolo_main(
    const float* __restrict__ pred, const float* __restrict__ target,
    const int* __restrict__ choice, float* __restrict__ ws, int ncells)
{
    __shared__ float sbuf[2 * CPB * NCH];   // 30720 B: [pred chunk][target chunk]
    const int tid = threadIdx.x;
    const long long cell0 = (long long)blockIdx.x * CPB;
    const int remain = ncells - (int)cell0;

    if (remain >= CPB) {
        // fully coalesced: lane i loads base + i*16B -> 16 cache lines/instr,
        // every line requested exactly once
        const float4* Pg = (const float4*)(pred + cell0 * NCH);
        const float4* Tg = (const float4*)(target + cell0 * NCH);
        #pragma unroll
        for (int j = 0; j < 2 * NV / T; ++j) {   // 15 iters; k<NV wave-uniform
            int k = j * T + tid;
            float4 v;
            if (k < NV) v = Pg[k]; else v = Tg[k - NV];
            *(float4*)&sbuf[k * 4] = v;
        }
    } else {
        int nf = remain * NCH;
        for (int idx = tid; idx < nf; idx += T) {
            sbuf[idx]             = pred[cell0 * NCH + idx];
            sbuf[CPB * NCH + idx] = target[cell0 * NCH + idx];
        }
    }
    __syncthreads();

    float s_loc = 0.f, s_ce = 0.f, s_obj = 0.f, s_no = 0.f;
    float n_obj = 0.f, n_no = 0.f;

    if (cell0 + tid < ncells) {
        const float* sp  = &sbuf[tid * NCH];             // 120*tid B, 8-aligned
        const float* stt = &sbuf[CPB * NCH + tid * NCH];
        float p[NCH], t[NCH];
        #pragma unroll
        for (int i = 0; i < NCH / 2; ++i) {
            float2 v = *(const float2*)&sp[2 * i];  p[2*i] = v.x; p[2*i+1] = v.y;
        }
        #pragma unroll
        for (int i = 0; i < NCH / 2; ++i) {
            float2 w = *(const float2*)&stt[2 * i]; t[2*i] = w.x; t[2*i+1] = w.y;
        }
        bool c = choice[cell0 + tid] != 0;   // coalesced 4B/lane

        float tconf = t[4];
        bool  obj = tconf > 0.0f;
        float m = obj ? 1.0f : 0.0f;

        float pxy0 = c ? p[0] : p[5];
        float pxy1 = c ? p[1] : p[6];
        float pwh0 = c ? p[2] : p[7];
        float pwh1 = c ? p[3] : p[8];
        float pobj = c ? p[4] : p[9];
        float txy0 = c ? t[0] : t[5];
        float txy1 = c ? t[1] : t[6];
        float twh0 = c ? t[2] : t[7];
        float twh1 = c ? t[3] : t[8];
        if (!obj) { twh0 = 1.0f; twh1 = 1.0f; }
        float tobj = c ? tconf : t[9];

        float dx = pxy0 - txy0, dy = pxy1 - txy1;
        float dw = pwh0 - sqrtf(twh0), dh = pwh1 - sqrtf(twh1);
        s_loc = m * (0.5f * (dx * dx + dy * dy) + 0.5f * (dw * dw + dh * dh));

        float dob = pobj - tobj;
        s_obj = m * dob * dob;

        float nm = (tconf == 0.0f) ? 1.0f : 0.0f;
        float d4 = p[4] - tconf, d9 = p[9] - t[9];
        s_no = nm * (d4 * d4 + d9 * d9);

        n_obj = m;
        n_no  = nm;

        int   tcls  = 0;
        float tbest = t[10];
        #pragma unroll
        for (int i = 1; i < CC; ++i) {
            float v = t[10 + i];
            if (v > tbest) { tbest = v; tcls = i; }
        }
        float mx = p[10];
        #pragma unroll
        for (int i = 1; i < CC; ++i) mx = fmaxf(mx, p[10 + i]);
        float e[CC];
        float Z = 0.f;
        #pragma unroll
        for (int i = 0; i < CC; ++i) { e[i] = __expf(p[10 + i] - mx); Z += e[i]; }
        float rZ = 1.0f / Z;
        float Z2 = 0.f, sm_t = 0.f;
        #pragma unroll
        for (int i = 0; i < CC; ++i) {
            float sm = e[i] * rZ;          // in (0,1] -> exp safe
            Z2 += __expf(sm);
            if (i == tcls) sm_t = sm;
        }
        s_ce = m * (__logf(Z2) - sm_t);
    }

    // wave(64) shuffle reduction of the 6 partials
    #pragma unroll
    for (int off = 32; off > 0; off >>= 1) {
        s_loc += __shfl_down(s_loc, off);
        s_ce  += __shfl_down(s_ce,  off);
        s_obj += __shfl_down(s_obj, off);
        s_no  += __shfl_down(s_no,  off);
        n_obj += __shfl_down(n_obj, off);
        n_no  += __shfl_down(n_no,  off);
    }

    __shared__ float red[2][6];
    int wave = tid >> 6;
    int lane = tid & 63;
    if (lane == 0) {
        red[wave][0] = s_loc; red[wave][1] = s_ce;  red[wave][2] = s_obj;
        red[wave][3] = s_no;  red[wave][4] = n_obj; red[wave][5] = n_no;
    }
    __syncthreads();
    // NO atomics: private row per block, plain store
    if (tid < 6) {
        float v = red[0][tid] + red[1][tid];
        ws[(size_t)blockIdx.x * ROW + tid] = v;
    }
}

__global__ __launch_bounds__(256) void yolo_reduce(
    const float* __restrict__ ws, float* __restrict__ out, int nb)
{
    float s[6] = {0.f, 0.f, 0.f, 0.f, 0.f, 0.f};
    for (int b = threadIdx.x; b < nb; b += 256) {
        #pragma unroll
        for (int j = 0; j < 6; ++j) s[j] += ws[(size_t)b * ROW + j];
    }
    #pragma unroll
    for (int off = 32; off > 0; off >>= 1) {
        #pragma unroll
        for (int j = 0; j < 6; ++j) s[j] += __shfl_down(s[j], off);
    }
    __shared__ float red[4][6];
    int wave = threadIdx.x >> 6;
    int lane = threadIdx.x & 63;
    if (lane == 0) {
        #pragma unroll
        for (int j = 0; j < 6; ++j) red[wave][j] = s[j];
    }
    __syncthreads();
    if (threadIdx.x == 0) {
        float t[6];
        #pragma unroll
        for (int j = 0; j < 6; ++j)
            t[j] = red[0][j] + red[1][j] + red[2][j] + red[3][j];
        out[0] = 5.0f * t[0];                     // loc_loss  (L_COORD = 5)
        out[1] = t[1] / fmaxf(t[4], 1.0f);        // cls_loss
        out[2] = t[2];                            // obj_loss
        out[3] = 0.5f * t[3] / fmaxf(t[5], 1.0f); // noobj_loss (L_NOOBJ = 0.5)
    }
}

extern "C" void kernel_launch(void* const* d_in, const int* in_sizes, int n_in,
                              void* d_out, int out_size, void* d_ws, size_t ws_size,
                              hipStream_t stream) {
    const float* pred   = (const float*)d_in[0];
    const float* target = (const float*)d_in[1];
    const int*   choice = (const int*)d_in[2];
    float* out = (float*)d_out;
    float* ws  = (float*)d_ws;

    int ncells = in_sizes[2];                 // BATCH * S * S = 802816
    int blocks = (ncells + CPB - 1) / CPB;    // 6272
    // ws usage: blocks * ROW * 4 B = 200 KB; every row written before read
    yolo_main<<<blocks, T, 0, stream>>>(pred, target, choice, ws, ncells);
    yolo_reduce<<<1, 256, 0, stream>>>(ws, out, blocks);
}

// Round 5
// 211.383 us; speedup vs baseline: 1.4366x; 1.0139x over previous
//
#include <hip/hip_runtime.h>
#include <math.h>

// YOLO loss: pred/target (BATCH,7,7,30) f32, choice (BATCH,7,7) i32
// -> 4 scalars (loc, cls, obj, noobj).
// Round-5 theory: rounds 3+4 both plateau at ~2.5 TB/s effective read rate
// with ~80% stall cycles regardless of access pattern -> memory duty-cycle
// loss from burst-then-drain (vmcnt(0)+barrier) lockstep. Fix: persistent
// blocks, grid-stride over chunks, VGPR prefetch of chunk i+1 issued BEFORE
// computing chunk i (single LDS buffer; prefetch lives in registers).
// Keeps: coalesced float4 staging (r2), no same-address atomics (r3).

constexpr int NCH = 30;    // 5*B + C
constexpr int CC  = 20;    // classes
constexpr int ROW = 8;     // floats per block's partial row (32 B)
constexpr int T   = 256;   // threads per block (4 waves)
constexpr int CPB = 128;   // cells per chunk
constexpr int NF4 = CPB * NCH * 2 / 4;  // 1920 float4 per chunk (pred+target)
constexpr int HF4 = NF4 / 2;            // 960: pred/target boundary
constexpr int GRID = 1280; // 5 blocks/CU * 256 CU

__device__ __forceinline__ void issue_chunk(
    const float* __restrict__ pred, const float* __restrict__ target,
    const int* __restrict__ choice, int cc, int ncells, int tid,
    float4 (&r)[8], int& ci)
{
    long long base = (long long)cc * CPB;
    if (base + CPB <= (long long)ncells) {
        const float4* Pb = (const float4*)(pred + base * NCH);
        const float4* Tb = (const float4*)(target + base * NCH);
        #pragma unroll
        for (int j = 0; j < 8; ++j) {
            int k = j * T + tid;            // guards wave-uniform (T mult of 64)
            if (k < NF4) r[j] = (k < HF4) ? Pb[k] : Tb[k - HF4];
        }
    } else {
        int nfl = (int)(ncells - base) * NCH;   // valid floats per array
        const float* Pf = pred + base * NCH;
        const float* Tf = target + base * NCH;
        #pragma unroll
        for (int j = 0; j < 8; ++j) {
            int k = j * T + tid;
            float4 v = make_float4(0.f, 0.f, 0.f, 0.f);
            if (k < NF4) {
                int kk = (k < HF4) ? k : k - HF4;
                const float* src = (k < HF4) ? Pf : Tf;
                int b = 4 * kk;
                if (b + 0 < nfl) v.x = src[b + 0];
                if (b + 1 < nfl) v.y = src[b + 1];
                if (b + 2 < nfl) v.z = src[b + 2];
                if (b + 3 < nfl) v.w = src[b + 3];
            }
            r[j] = v;
        }
    }
    if (tid < CPB) {
        long long ce = base + tid;
        ci = (ce < (long long)ncells) ? choice[ce] : 0;
    }
}

__global__ __launch_bounds__(T) void yolo_main(
    const float* __restrict__ pred, const float* __restrict__ target,
    const int* __restrict__ choice, float* __restrict__ ws,
    int ncells, int nchunks)
{
    __shared__ float sbuf[2 * CPB * NCH];   // 30720 B: [pred chunk][target chunk]
    const int tid = threadIdx.x;

    float a_loc = 0.f, a_ce = 0.f, a_obj = 0.f, a_no = 0.f;
    float a_nob = 0.f, a_nno = 0.f;

    float4 r[8];
    int ci = 0;
    int c = blockIdx.x;
    if (c < nchunks) issue_chunk(pred, target, choice, c, ncells, tid, r, ci);

    for (; c < nchunks; c += GRID) {
        __syncthreads();                    // prev compute done reading sbuf
        // implicit vmcnt wait: ds_write consumes r
        #pragma unroll
        for (int j = 0; j < 8; ++j) {
            int k = j * T + tid;
            if (k < NF4) *(float4*)&sbuf[k * 4] = r[j];
        }
        int myc = ci;
        __syncthreads();                    // chunk c visible

        int cn = c + GRID;                  // PREFETCH next chunk before compute
        if (cn < nchunks) issue_chunk(pred, target, choice, cn, ncells, tid, r, ci);

        if (tid < CPB && (long long)c * CPB + tid < ncells) {
            const float* sp  = &sbuf[tid * NCH];
            const float* stt = &sbuf[CPB * NCH + tid * NCH];
            float p[NCH], t[NCH];
            #pragma unroll
            for (int i = 0; i < NCH / 2; ++i) {
                float2 v = *(const float2*)&sp[2 * i];  p[2*i] = v.x; p[2*i+1] = v.y;
            }
            #pragma unroll
            for (int i = 0; i < NCH / 2; ++i) {
                float2 w = *(const float2*)&stt[2 * i]; t[2*i] = w.x; t[2*i+1] = w.y;
            }
            bool csel = myc != 0;

            float tconf = t[4];
            bool  obj = tconf > 0.0f;
            float m = obj ? 1.0f : 0.0f;

            float pxy0 = csel ? p[0] : p[5];
            float pxy1 = csel ? p[1] : p[6];
            float pwh0 = csel ? p[2] : p[7];
            float pwh1 = csel ? p[3] : p[8];
            float pobj = csel ? p[4] : p[9];
            float txy0 = csel ? t[0] : t[5];
            float txy1 = csel ? t[1] : t[6];
            float twh0 = csel ? t[2] : t[7];
            float twh1 = csel ? t[3] : t[8];
            if (!obj) { twh0 = 1.0f; twh1 = 1.0f; }
            float tobj = csel ? tconf : t[9];

            float dx = pxy0 - txy0, dy = pxy1 - txy1;
            float dw = pwh0 - sqrtf(twh0), dh = pwh1 - sqrtf(twh1);
            a_loc += m * (0.5f * (dx*dx + dy*dy) + 0.5f * (dw*dw + dh*dh));

            float dob = pobj - tobj;
            a_obj += m * dob * dob;

            float nm = (tconf == 0.0f) ? 1.0f : 0.0f;
            float d4 = p[4] - tconf, d9 = p[9] - t[9];
            a_no += nm * (d4 * d4 + d9 * d9);

            a_nob += m;
            a_nno += nm;

            int   tcls  = 0;
            float tbest = t[10];
            #pragma unroll
            for (int i = 1; i < CC; ++i) {
                float v = t[10 + i];
                if (v > tbest) { tbest = v; tcls = i; }
            }
            float mx = p[10];
            #pragma unroll
            for (int i = 1; i < CC; ++i) mx = fmaxf(mx, p[10 + i]);
            float e[CC];
            float Z = 0.f;
            #pragma unroll
            for (int i = 0; i < CC; ++i) { e[i] = __expf(p[10+i] - mx); Z += e[i]; }
            float rZ = 1.0f / Z;
            float Z2 = 0.f, sm_t = 0.f;
            #pragma unroll
            for (int i = 0; i < CC; ++i) {
                float sm = e[i] * rZ;          // in (0,1] -> exp safe
                Z2 += __expf(sm);
                if (i == tcls) sm_t = sm;
            }
            a_ce += m * (__logf(Z2) - sm_t);
        }
    }

    // wave(64) shuffle reduction of the 6 accumulators
    #pragma unroll
    for (int off = 32; off > 0; off >>= 1) {
        a_loc += __shfl_down(a_loc, off);
        a_ce  += __shfl_down(a_ce,  off);
        a_obj += __shfl_down(a_obj, off);
        a_no  += __shfl_down(a_no,  off);
        a_nob += __shfl_down(a_nob, off);
        a_nno += __shfl_down(a_nno, off);
    }

    __shared__ float red[4][6];
    int wave = tid >> 6;
    int lane = tid & 63;
    if (lane == 0) {
        red[wave][0] = a_loc; red[wave][1] = a_ce;  red[wave][2] = a_obj;
        red[wave][3] = a_no;  red[wave][4] = a_nob; red[wave][5] = a_nno;
    }
    __syncthreads();
    if (tid < 6) {   // NO atomics: private row per block
        float v = red[0][tid] + red[1][tid] + red[2][tid] + red[3][tid];
        ws[(size_t)blockIdx.x * ROW + tid] = v;
    }
}

__global__ __launch_bounds__(256) void yolo_reduce(
    const float* __restrict__ ws, float* __restrict__ out, int nb)
{
    float s[6] = {0.f, 0.f, 0.f, 0.f, 0.f, 0.f};
    for (int b = threadIdx.x; b < nb; b += 256) {
        #pragma unroll
        for (int j = 0; j < 6; ++j) s[j] += ws[(size_t)b * ROW + j];
    }
    #pragma unroll
    for (int off = 32; off > 0; off >>= 1) {
        #pragma unroll
        for (int j = 0; j < 6; ++j) s[j] += __shfl_down(s[j], off);
    }
    __shared__ float red[4][6];
    int wave = threadIdx.x >> 6;
    int lane = threadIdx.x & 63;
    if (lane == 0) {
        #pragma unroll
        for (int j = 0; j < 6; ++j) red[wave][j] = s[j];
    }
    __syncthreads();
    if (threadIdx.x == 0) {
        float t[6];
        #pragma unroll
        for (int j = 0; j < 6; ++j)
            t[j] = red[0][j] + red[1][j] + red[2][j] + red[3][j];
        out[0] = 5.0f * t[0];                     // loc_loss  (L_COORD = 5)
        out[1] = t[1] / fmaxf(t[4], 1.0f);        // cls_loss
        out[2] = t[2];                            // obj_loss
        out[3] = 0.5f * t[3] / fmaxf(t[5], 1.0f); // noobj_loss (L_NOOBJ = 0.5)
    }
}

extern "C" void kernel_launch(void* const* d_in, const int* in_sizes, int n_in,
                              void* d_out, int out_size, void* d_ws, size_t ws_size,
                              hipStream_t stream) {
    const float* pred   = (const float*)d_in[0];
    const float* target = (const float*)d_in[1];
    const int*   choice = (const int*)d_in[2];
    float* out = (float*)d_out;
    float* ws  = (float*)d_ws;

    int ncells  = in_sizes[2];                   // BATCH * S * S = 802816
    int nchunks = (ncells + CPB - 1) / CPB;      // 6272 exactly
    int grid    = GRID < nchunks ? GRID : nchunks;
    // ws usage: GRID * ROW * 4 B = 40 KB; rows [0,grid) all written before read
    yolo_main<<<grid, T, 0, stream>>>(pred, target, choice, ws, ncells, nchunks);
    yolo_reduce<<<1, 256, 0, stream>>>(ws, out, grid);
}

// Round 7
// 193.844 us; speedup vs baseline: 1.5666x; 1.0905x over previous
//
#include <hip/hip_runtime.h>
#include <math.h>

// YOLO loss: pred/target (BATCH,7,7,30) f32, choice (BATCH,7,7) i32
// -> 4 scalars (loc, cls, obj, noobj).
// Round-7 = round-6 with the compile fix: __builtin_nontemporal_load needs a
// native clang vector type, not HIP_vector_type (float4).
// Theory (r6): r1/r3/r4/r5 all converge to ~75us (even fully-L3-warm),
// insensitive to request count, duty cycle, atomics. The only invariant is
// unique L1 line fills: ~5900 lines/CU at ~30 cyc/fill = 4.2 B/cyc/CU.
// => L1 allocation rate is the cap. Fix: NON-TEMPORAL (no-allocate) loads on
// the staging stream; every line is consumed exactly once.

typedef float vf4 __attribute__((ext_vector_type(4)));   // nt-load compatible

constexpr int NCH = 30;    // 5*B + C
constexpr int CC  = 20;    // classes
constexpr int ROW = 8;     // floats per block's partial row (32 B)
constexpr int T   = 256;   // threads per block (4 waves)
constexpr int CPB = 128;   // cells per chunk
constexpr int NF4 = CPB * NCH * 2 / 4;  // 1920 vf4 per chunk (pred+target)
constexpr int HF4 = NF4 / 2;            // 960: pred/target boundary
constexpr int GRID = 1280; // 5 blocks/CU * 256 CU

__device__ __forceinline__ void issue_chunk(
    const float* __restrict__ pred, const float* __restrict__ target,
    const int* __restrict__ choice, int cc, int ncells, int tid,
    vf4 (&r)[8], int& ci)
{
    long long base = (long long)cc * CPB;
    if (base + CPB <= (long long)ncells) {
        const vf4* Pb = (const vf4*)(pred + base * NCH);
        const vf4* Tb = (const vf4*)(target + base * NCH);
        #pragma unroll
        for (int j = 0; j < 8; ++j) {
            int k = j * T + tid;            // guards wave-uniform (T mult of 64)
            if (k < NF4)
                r[j] = (k < HF4) ? __builtin_nontemporal_load(&Pb[k])
                                 : __builtin_nontemporal_load(&Tb[k - HF4]);
        }
    } else {
        int nfl = (int)(ncells - base) * NCH;   // valid floats per array
        const float* Pf = pred + base * NCH;
        const float* Tf = target + base * NCH;
        #pragma unroll
        for (int j = 0; j < 8; ++j) {
            int k = j * T + tid;
            vf4 v = (vf4)(0.f, 0.f, 0.f, 0.f);
            if (k < NF4) {
                int kk = (k < HF4) ? k : k - HF4;
                const float* src = (k < HF4) ? Pf : Tf;
                int b = 4 * kk;
                if (b + 0 < nfl) v.x = src[b + 0];
                if (b + 1 < nfl) v.y = src[b + 1];
                if (b + 2 < nfl) v.z = src[b + 2];
                if (b + 3 < nfl) v.w = src[b + 3];
            }
            r[j] = v;
        }
    }
    if (tid < CPB) {
        long long ce = base + tid;
        ci = (ce < (long long)ncells) ? __builtin_nontemporal_load(&choice[ce]) : 0;
    }
}

__global__ __launch_bounds__(T) void yolo_main(
    const float* __restrict__ pred, const float* __restrict__ target,
    const int* __restrict__ choice, float* __restrict__ ws,
    int ncells, int nchunks)
{
    __shared__ float sbuf[2 * CPB * NCH];   // 30720 B: [pred chunk][target chunk]
    const int tid = threadIdx.x;

    float a_loc = 0.f, a_ce = 0.f, a_obj = 0.f, a_no = 0.f;
    float a_nob = 0.f, a_nno = 0.f;

    vf4 r[8];
    int ci = 0;
    int c = blockIdx.x;
    if (c < nchunks) issue_chunk(pred, target, choice, c, ncells, tid, r, ci);

    for (; c < nchunks; c += GRID) {
        __syncthreads();                    // prev compute done reading sbuf
        #pragma unroll
        for (int j = 0; j < 8; ++j) {
            int k = j * T + tid;
            if (k < NF4) *(vf4*)&sbuf[k * 4] = r[j];
        }
        int myc = ci;
        __syncthreads();                    // chunk c visible

        int cn = c + GRID;                  // PREFETCH next chunk before compute
        if (cn < nchunks) issue_chunk(pred, target, choice, cn, ncells, tid, r, ci);

        if (tid < CPB && (long long)c * CPB + tid < ncells) {
            const float* sp  = &sbuf[tid * NCH];
            const float* stt = &sbuf[CPB * NCH + tid * NCH];
            float p[NCH], t[NCH];
            #pragma unroll
            for (int i = 0; i < NCH / 2; ++i) {
                float2 v = *(const float2*)&sp[2 * i];  p[2*i] = v.x; p[2*i+1] = v.y;
            }
            #pragma unroll
            for (int i = 0; i < NCH / 2; ++i) {
                float2 w = *(const float2*)&stt[2 * i]; t[2*i] = w.x; t[2*i+1] = w.y;
            }
            bool csel = myc != 0;

            float tconf = t[4];
            bool  obj = tconf > 0.0f;
            float m = obj ? 1.0f : 0.0f;

            float pxy0 = csel ? p[0] : p[5];
            float pxy1 = csel ? p[1] : p[6];
            float pwh0 = csel ? p[2] : p[7];
            float pwh1 = csel ? p[3] : p[8];
            float pobj = csel ? p[4] : p[9];
            float txy0 = csel ? t[0] : t[5];
            float txy1 = csel ? t[1] : t[6];
            float twh0 = csel ? t[2] : t[7];
            float twh1 = csel ? t[3] : t[8];
            if (!obj) { twh0 = 1.0f; twh1 = 1.0f; }
            float tobj = csel ? tconf : t[9];

            float dx = pxy0 - txy0, dy = pxy1 - txy1;
            float dw = pwh0 - sqrtf(twh0), dh = pwh1 - sqrtf(twh1);
            a_loc += m * (0.5f * (dx*dx + dy*dy) + 0.5f * (dw*dw + dh*dh));

            float dob = pobj - tobj;
            a_obj += m * dob * dob;

            float nm = (tconf == 0.0f) ? 1.0f : 0.0f;
            float d4 = p[4] - tconf, d9 = p[9] - t[9];
            a_no += nm * (d4 * d4 + d9 * d9);

            a_nob += m;
            a_nno += nm;

            int   tcls  = 0;
            float tbest = t[10];
            #pragma unroll
            for (int i = 1; i < CC; ++i) {
                float v = t[10 + i];
                if (v > tbest) { tbest = v; tcls = i; }
            }
            float mx = p[10];
            #pragma unroll
            for (int i = 1; i < CC; ++i) mx = fmaxf(mx, p[10 + i]);
            float e[CC];
            float Z = 0.f;
            #pragma unroll
            for (int i = 0; i < CC; ++i) { e[i] = __expf(p[10+i] - mx); Z += e[i]; }
            float rZ = 1.0f / Z;
            float Z2 = 0.f, sm_t = 0.f;
            #pragma unroll
            for (int i = 0; i < CC; ++i) {
                float sm = e[i] * rZ;          // in (0,1] -> exp safe
                Z2 += __expf(sm);
                if (i == tcls) sm_t = sm;
            }
            a_ce += m * (__logf(Z2) - sm_t);
        }
    }

    // wave(64) shuffle reduction of the 6 accumulators
    #pragma unroll
    for (int off = 32; off > 0; off >>= 1) {
        a_loc += __shfl_down(a_loc, off);
        a_ce  += __shfl_down(a_ce,  off);
        a_obj += __shfl_down(a_obj, off);
        a_no  += __shfl_down(a_no,  off);
        a_nob += __shfl_down(a_nob, off);
        a_nno += __shfl_down(a_nno, off);
    }

    __shared__ float red[4][6];
    int wave = tid >> 6;
    int lane = tid & 63;
    if (lane == 0) {
        red[wave][0] = a_loc; red[wave][1] = a_ce;  red[wave][2] = a_obj;
        red[wave][3] = a_no;  red[wave][4] = a_nob; red[wave][5] = a_nno;
    }
    __syncthreads();
    if (tid < 6) {   // NO atomics: private row per block
        float v = red[0][tid] + red[1][tid] + red[2][tid] + red[3][tid];
        ws[(size_t)blockIdx.x * ROW + tid] = v;
    }
}

__global__ __launch_bounds__(256) void yolo_reduce(
    const float* __restrict__ ws, float* __restrict__ out, int nb)
{
    float s[6] = {0.f, 0.f, 0.f, 0.f, 0.f, 0.f};
    for (int b = threadIdx.x; b < nb; b += 256) {
        #pragma unroll
        for (int j = 0; j < 6; ++j) s[j] += ws[(size_t)b * ROW + j];
    }
    #pragma unroll
    for (int off = 32; off > 0; off >>= 1) {
        #pragma unroll
        for (int j = 0; j < 6; ++j) s[j] += __shfl_down(s[j], off);
    }
    __shared__ float red[4][6];
    int wave = threadIdx.x >> 6;
    int lane = threadIdx.x & 63;
    if (lane == 0) {
        #pragma unroll
        for (int j = 0; j < 6; ++j) red[wave][j] = s[j];
    }
    __syncthreads();
    if (threadIdx.x == 0) {
        float t[6];
        #pragma unroll
        for (int j = 0; j < 6; ++j)
            t[j] = red[0][j] + red[1][j] + red[2][j] + red[3][j];
        out[0] = 5.0f * t[0];                     // loc_loss  (L_COORD = 5)
        out[1] = t[1] / fmaxf(t[4], 1.0f);        // cls_loss
        out[2] = t[2];                            // obj_loss
        out[3] = 0.5f * t[3] / fmaxf(t[5], 1.0f); // noobj_loss (L_NOOBJ = 0.5)
    }
}

extern "C" void kernel_launch(void* const* d_in, const int* in_sizes, int n_in,
                              void* d_out, int out_size, void* d_ws, size_t ws_size,
                              hipStream_t stream) {
    const float* pred   = (const float*)d_in[0];
    const float* target = (const float*)d_in[1];
    const int*   choice = (const int*)d_in[2];
    float* out = (float*)d_out;
    float* ws  = (float*)d_ws;

    int ncells  = in_sizes[2];                   // BATCH * S * S = 802816
    int nchunks = (ncells + CPB - 1) / CPB;      // 6272 exactly
    int grid    = GRID < nchunks ? GRID : nchunks;
    // ws usage: GRID * ROW * 4 B = 40 KB; rows [0,grid) all written before read
    yolo_main<<<grid, T, 0, stream>>>(pred, target, choice, ws, ncells, nchunks);
    yolo_reduce<<<1, 256, 0, stream>>>(ws, out, grid);
}